// Round 1
// baseline (261.933 us; speedup 1.0000x reference)
//
#include <hip/hip_runtime.h>
#include <cmath>

#define Bb 32
#define Ss 2048
#define Hh 768
#define Oo 768
#define Kk 64

// Kernel A: per-batch fused scores + dedupe-softmax + aw scatter + weighted pool.
// grid 32 x 256 (4 waves/block). Rows read in the score pass are L2-hot for the
// pool pass (196 KB/block << 4 MiB/XCD).
__global__ __launch_bounds__(256) void attn_pool_kernel(
    const float* __restrict__ hidden,
    const int*   __restrict__ idxs,
    const float* __restrict__ subj,
    const float* __restrict__ Wa,
    const float* __restrict__ ba,
    float* __restrict__ pooled,   // ws: [B*H]
    float* __restrict__ aw_out)   // out + B*O: [B*S]
{
    const int b    = blockIdx.x;
    const int tid  = threadIdx.x;
    const int lane = tid & 63;
    const int w    = tid >> 6;    // 0..3

    __shared__ float s_sc[Kk];
    __shared__ float s_aw[Kk];
    __shared__ int   s_idx[Kk];
    __shared__ float s_sconst;

    if (tid < Kk) s_idx[tid] = idxs[b * Kk + tid];

    // zero this batch's attention-weight slab (2048 floats = 512 float4)
    float4* z4 = (float4*)(aw_out + (size_t)b * Ss);
    z4[tid]       = make_float4(0.f, 0.f, 0.f, 0.f);
    z4[tid + 256] = make_float4(0.f, 0.f, 0.f, 0.f);

    // sconst = subj[b] . Wa[0:H] + ba   (wave 0)
    if (w == 0) {
        const float4* s4  = (const float4*)(subj + b * Hh);
        const float4* wa4 = (const float4*)Wa;
        float p = 0.f;
        #pragma unroll
        for (int t = 0; t < 3; ++t) {
            const float4 r = s4[lane + 64 * t];
            const float4 q = wa4[lane + 64 * t];
            p += r.x * q.x + r.y * q.y + r.z * q.z + r.w * q.w;
        }
        #pragma unroll
        for (int m = 32; m >= 1; m >>= 1) p += __shfl_xor(p, m);
        if (lane == 0) s_sconst = p + ba[0];
    }
    __syncthreads();

    // scores: wave w owns j = w*16 .. w*16+15; Wa[H:2H] fragment hoisted.
    {
        const float4* wa4 = (const float4*)(Wa + Hh);
        const float4 q0 = wa4[lane];
        const float4 q1 = wa4[lane + 64];
        const float4 q2 = wa4[lane + 128];
        #pragma unroll 2
        for (int jj = 0; jj < 16; ++jj) {
            const int j = w * 16 + jj;
            const float4* r4 =
                (const float4*)(hidden + ((size_t)b * Ss + s_idx[j]) * Hh);
            const float4 r0 = r4[lane];
            const float4 r1 = r4[lane + 64];
            const float4 r2 = r4[lane + 128];
            float p = r0.x * q0.x + r0.y * q0.y + r0.z * q0.z + r0.w * q0.w
                    + r1.x * q1.x + r1.y * q1.y + r1.z * q1.z + r1.w * q1.w
                    + r2.x * q2.x + r2.y * q2.y + r2.z * q2.z + r2.w * q2.w;
            #pragma unroll
            for (int m = 32; m >= 1; m >>= 1) p += __shfl_xor(p, m);
            if (lane == 0) s_sc[j] = p;
        }
    }
    __syncthreads();

    // softmax with duplicate-index dedupe (idxs sorted), scatter to aw_out.
    if (tid < Kk) {
        const float sc = s_sc[tid] + s_sconst;
        const bool active = (tid == 0) || (s_idx[tid] != s_idx[tid - 1]);
        float v = active ? sc : -3.0e38f;
        float mx = v;
        #pragma unroll
        for (int m = 32; m >= 1; m >>= 1) mx = fmaxf(mx, __shfl_xor(mx, m));
        const float e = active ? expf(sc - mx) : 0.f;
        float sum = e;
        #pragma unroll
        for (int m = 32; m >= 1; m >>= 1) sum += __shfl_xor(sum, m);
        const float wgt = e / sum;       // duplicates get 0
        s_aw[tid] = wgt;
        if (active) aw_out[(size_t)b * Ss + s_idx[tid]] = wgt;
    }
    __syncthreads();

    // pooled[b, :] — rows L2-hot from the score pass. thread owns h = tid, tid+256, tid+512.
    {
        float a0 = 0.f, a1 = 0.f, a2 = 0.f;
        #pragma unroll 8
        for (int j = 0; j < Kk; ++j) {
            const float wj = s_aw[j];
            const float* row = hidden + ((size_t)b * Ss + s_idx[j]) * Hh;
            a0 = fmaf(wj, row[tid],       a0);
            a1 = fmaf(wj, row[tid + 256], a1);
            a2 = fmaf(wj, row[tid + 512], a2);
        }
        pooled[b * Hh + tid]       = a0;
        pooled[b * Hh + tid + 256] = a1;
        pooled[b * Hh + tid + 512] = a2;
    }
}

// Kernel B: out = tanh(pooled @ Wo + bo). grid 192 (b = blk/6, oc = blk%6),
// block 1024 = 8 h-groups x 128 o. 96 MACs/thread -> ~12 pipelined load rounds.
__global__ __launch_bounds__(1024) void gemm_kernel(
    const float* __restrict__ pooled,
    const float* __restrict__ Wo,
    const float* __restrict__ bo,
    float* __restrict__ out)
{
    const int b   = blockIdx.x / 6;
    const int oc  = blockIdx.x % 6;
    const int tid = threadIdx.x;

    __shared__ float s_pool[Hh];
    __shared__ float s_part[8 * 128];

    if (tid < Hh) s_pool[tid] = pooled[b * Hh + tid];
    __syncthreads();

    const int ol = tid & 127;
    const int o  = oc * 128 + ol;
    const int hg = tid >> 7;          // 0..7
    const int h0 = hg * 96;
    float acc = 0.f;
    #pragma unroll 8
    for (int h = h0; h < h0 + 96; ++h)
        acc = fmaf(s_pool[h], Wo[h * Oo + o], acc);
    s_part[hg * 128 + ol] = acc;
    __syncthreads();

    if (tid < 128) {
        float s = bo[oc * 128 + tid];
        #pragma unroll
        for (int g = 0; g < 8; ++g) s += s_part[g * 128 + tid];
        out[b * Oo + oc * 128 + tid] = tanhf(s);
    }
}

extern "C" void kernel_launch(void* const* d_in, const int* in_sizes, int n_in,
                              void* d_out, int out_size, void* d_ws, size_t ws_size,
                              hipStream_t stream) {
    const float* hidden = (const float*)d_in[0];
    const int*   idxs   = (const int*)d_in[1];
    const float* subj   = (const float*)d_in[2];
    const float* Wa     = (const float*)d_in[3];
    const float* ba     = (const float*)d_in[4];
    const float* Wo     = (const float*)d_in[5];
    const float* bo     = (const float*)d_in[6];

    float* out    = (float*)d_out;            // transformed: B*O floats
    float* aw_out = out + Bb * Oo;            // attention_weights: B*S floats
    float* pooled = (float*)d_ws;             // [B*H]

    attn_pool_kernel<<<Bb, 256, 0, stream>>>(hidden, idxs, subj, Wa, ba, pooled, aw_out);
    gemm_kernel<<<Bb * 6, 1024, 0, stream>>>(pooled, Wo, bo, out);
}